// Round 2
// 1322.312 us; speedup vs baseline: 1.0088x; 1.0088x over previous
//
#include <hip/hip_runtime.h>
#include <math.h>

constexpr int kS  = 384;
constexpr int kS1 = 385;
constexpr int kH  = 8;
constexpr int kB  = 32;
constexpr int kD  = 256;
constexpr float kEPS = 1e-8f;
// (1/0.05) * log2(e)
constexpr float kNEG_INV_EPS_LOG2E = 28.853900817779268f;

__device__ __forceinline__ float waveReduceSum(float v) {
    #pragma unroll
    for (int m = 1; m < 64; m <<= 1) v += __shfl_xor(v, m);
    return v;
}
__device__ __forceinline__ float waveReduceMax(float v) {
    #pragma unroll
    for (int m = 1; m < 64; m <<= 1) v = fmaxf(v, __shfl_xor(v, m));
    return v;
}

// Per-head SYM scratch lives in the attn output region (overwritten by k2).
// 385*385*4B == 4 (mod 16), so pad each head's base to 16B alignment for
// float4 row reads. Slack per head: 385^2 - 384^2 = 769 floats >= 384(rs)+6(mx)+3(pad).
__device__ __forceinline__ size_t symBase(int head) {
    return (size_t)head * (kS1 * kS1) + (size_t)((4 - (head & 3)) & 3);
}

// ---------------------------------------------------------------------------
// K1a: symmetrize P -> SYM, full rowsums + per-strip max.
// Block = one (head, 64-row strip). grid (6, 256), 256 threads.
// Coalesced loads, transpose via LDS tile. No atomics: each block owns its
// 64 rows completely (reads the row strip + the matching column strip).
// ---------------------------------------------------------------------------
__global__ __launch_bounds__(256) void k1a_sym(
    const float* __restrict__ shared_attn,   // [B,H,385,385]
    float* __restrict__ sym_ws)              // attn region (scratch)
{
    const int head = blockIdx.y;
    const int ti   = blockIdx.x;             // row-strip index 0..5
    const int tid  = threadIdx.x;
    const int c    = tid & 63;               // column-in-tile == lane
    const int w    = tid >> 6;               // wave 0..3

    __shared__ float tB[64 * 65];
    __shared__ float wredA[4];

    const float* P = shared_attn + (size_t)head * (kS1 * kS1);
    float* SYM = sym_ws + symBase(head);
    float* rs  = SYM + kS * kS;              // [384] rowsums
    float* mxs = rs + kS;                    // [6] per-strip max

    float rs_part[16];
    #pragma unroll
    for (int k = 0; k < 16; ++k) rs_part[k] = 0.f;
    float mymax = 0.f;                       // P >= 0 (softmax), so 0 is safe

    for (int tj = 0; tj < 6; ++tj) {
        __syncthreads();
        // transpose source tile: P[tj-strip rows, ti-strip cols]
        for (int e = tid; e < 4096; e += 256) {
            int r = e >> 6, cc = e & 63;
            tB[r * 65 + cc] = P[(size_t)(1 + tj * 64 + r) * kS1 + (1 + ti * 64 + cc)];
        }
        __syncthreads();
        #pragma unroll
        for (int k = 0; k < 16; ++k) {
            int r = w + 4 * k;               // rows w, w+4, ..., w+60 per wave
            float av = P[(size_t)(1 + ti * 64 + r) * kS1 + (1 + tj * 64 + c)];
            float v  = 0.5f * (av + tB[c * 65 + r]);
            mymax = fmaxf(mymax, v);
            rs_part[k] += v;
            SYM[(size_t)(ti * 64 + r) * kS + tj * 64 + c] = v;
        }
    }
    // row r = w+4k is fully held by wave w (lane = column): wave reductions
    #pragma unroll
    for (int k = 0; k < 16; ++k) {
        float s = waveReduceSum(rs_part[k]);
        if (c == 0) rs[ti * 64 + w + 4 * k] = s;
    }
    float wm = waveReduceMax(mymax);
    if (c == 0) wredA[w] = wm;
    __syncthreads();
    if (tid == 0)
        mxs[ti] = fmaxf(fmaxf(wredA[0], wredA[1]), fmaxf(wredA[2], wredA[3]));
}

// ---------------------------------------------------------------------------
// K1b: per-(b,h) entropic GW -> alpha[head]. One block per head (256 blocks).
// Streams SYM as float4 ROW reads (SYM bitwise symmetric -> row == column).
// K-matrix row lives in registers; Sinkhorn colsum via wave shuffles.
// ---------------------------------------------------------------------------
__global__ __launch_bounds__(384) void k1b_gw(
    const float* __restrict__ DG,            // [B,H,16,16]
    const float* __restrict__ bmarg,         // [B,H,16]
    float* __restrict__ sym_ws,              // attn region (scratch)
    float* __restrict__ alpha_out)           // [256]
{
    const int head = blockIdx.x;
    const int tid  = threadIdx.x;            // row index i
    const int lane = tid & 63, wid = tid >> 6;

    __shared__ __align__(16) float Ms[kS * 16];  // 24576B
    __shared__ float ravu[kS];
    __shared__ float part[6 * 16];
    __shared__ float C2l[256];
    __shared__ float bl16[16], cb16[16], cC216[16], vls[16];
    __shared__ float wred[6];

    float* SYM = sym_ws + symBase(head);
    const float* rs  = SYM + kS * kS;
    const float* mxp = rs + kS;

    if (tid < 256) C2l[tid] = DG[head * 256 + tid];
    if (tid >= 256 && tid < 272) bl16[tid - 256] = bmarg[head * 16 + (tid - 256)];

    const float tloc = rs[tid];
    float tw = waveReduceSum(tloc);
    if (lane == 0) wred[wid] = tw;
    __syncthreads();
    const float total = wred[0] + wred[1] + wred[2] + wred[3] + wred[4] + wred[5];
    const float mx = fmaxf(fmaxf(fmaxf(mxp[0], mxp[1]), fmaxf(mxp[2], mxp[3])),
                           fmaxf(mxp[4], mxp[5]));
    const float den_mx = fmaxf(mx, kEPS);
    const float inv_mx = 1.0f / den_mx;
    const float Sdeg   = total * inv_mx;
    const float den_a  = fmaxf(Sdeg, kEPS);
    const float a_reg  = (tloc * inv_mx) / den_a;
    ravu[tid] = a_reg;

    if (tid < 16) {
        float cb = 0.f, cc2 = 0.f;
        #pragma unroll
        for (int k = 0; k < 16; ++k) {
            cb += bl16[k] * C2l[tid * 16 + k];          // cb[l]  = sum_k b_k C2[l,k]
            float c2 = C2l[k * 16 + tid];               // C2[k,l]
            cc2 = fmaf(bl16[k] * c2, c2, cc2);          // cC2[l] = sum_k b_k C2[k,l]^2
        }
        cb16[tid] = cb; cC216[tid] = cc2;
    }
    __syncthreads();

    // ---- outer iter 1 (closed form: T = a (x) b), float4 row stream -------
    const float4* __restrict__ symrow = (const float4*)(SYM + (size_t)tid * kS);
    float t1 = 0.f, t2 = 0.f;
    #pragma unroll 4
    for (int s4 = 0; s4 < 96; ++s4) {
        float4 v4 = symrow[s4];
        const float* av = &ravu[s4 * 4];
        float dp;
        dp = fmaf(-inv_mx, v4.x, 1.0f); t1 = fmaf(dp, av[0], t1); t2 = fmaf(dp * dp, av[0], t2);
        dp = fmaf(-inv_mx, v4.y, 1.0f); t1 = fmaf(dp, av[1], t1); t2 = fmaf(dp * dp, av[1], t2);
        dp = fmaf(-inv_mx, v4.z, 1.0f); t1 = fmaf(dp, av[2], t1); t2 = fmaf(dp * dp, av[2], t2);
        dp = fmaf(-inv_mx, v4.w, 1.0f); t1 = fmaf(dp, av[3], t1); t2 = fmaf(dp * dp, av[3], t2);
    }
    const float cc1 = t2;    // cC1[i]

    float kreg[16], vreg[16];
    float u_i = 0.f;
    #pragma unroll
    for (int l = 0; l < 16; ++l)
        kreg[l] = exp2f((cc1 + cC216[l] - 2.0f * cb16[l] * t1) * (-kNEG_INV_EPS_LOG2E));

    auto sinkhorn = [&]() {
        #pragma unroll
        for (int l = 0; l < 16; ++l) vreg[l] = 1.0f;
        for (int it = 0; it < 20; ++it) {
            float su = 0.f;
            #pragma unroll
            for (int l = 0; l < 16; ++l) su = fmaf(kreg[l], vreg[l], su);
            u_i = a_reg / fmaxf(su, 1e-30f);
            // colsum dn[l] = sum_s K[s,l] u_s : wave-level shuffle partials
            #pragma unroll
            for (int l = 0; l < 16; ++l) {
                float t = waveReduceSum(kreg[l] * u_i);
                if (lane == 0) part[wid * 16 + l] = t;
            }
            __syncthreads();
            if (tid < 16) {
                float dn = part[tid] + part[16 + tid] + part[32 + tid] +
                           part[48 + tid] + part[64 + tid] + part[80 + tid];
                vls[tid] = bl16[tid] / fmaxf(dn, 1e-30f);
            }
            __syncthreads();
            #pragma unroll
            for (int l = 0; l < 16; ++l) vreg[l] = vls[l];
        }
    };

    sinkhorn();

    float tens16[16];
    #pragma unroll
    for (int l = 0; l < 16; ++l) tens16[l] = 0.f;

    for (int outer = 1; outer < 5; ++outer) {
        // ---- M-phase: Ms[s][l] = u_s * sum_k K[s,k] v_k C2[l,k] ----------
        {
            float wk[16];
            #pragma unroll
            for (int k = 0; k < 16; ++k) wk[k] = kreg[k] * vreg[k];
            float m[16];
            #pragma unroll
            for (int l = 0; l < 16; ++l) {
                float acc = 0.f;
                #pragma unroll
                for (int k = 0; k < 16; ++k) acc = fmaf(wk[k], C2l[l * 16 + k], acc);
                m[l] = acc * u_i;
            }
            float4* Ms4w = (float4*)Ms;
            Ms4w[tid * 4 + 0] = make_float4(m[0],  m[1],  m[2],  m[3]);
            Ms4w[tid * 4 + 1] = make_float4(m[4],  m[5],  m[6],  m[7]);
            Ms4w[tid * 4 + 2] = make_float4(m[8],  m[9],  m[10], m[11]);
            Ms4w[tid * 4 + 3] = make_float4(m[12], m[13], m[14], m[15]);
        }
        __syncthreads();
        // ---- stream: rd[l] = sum_s DP[i,s] * Ms[s][l], float4 row reads --
        float rd[16];
        #pragma unroll
        for (int l = 0; l < 16; ++l) rd[l] = 0.f;
        {
            const float4* Ms4 = (const float4*)Ms;
            #pragma unroll 2
            for (int s4 = 0; s4 < 96; ++s4) {
                float4 v4 = symrow[s4];
                #pragma unroll
                for (int j = 0; j < 4; ++j) {
                    float sym = (j == 0) ? v4.x : (j == 1) ? v4.y : (j == 2) ? v4.z : v4.w;
                    float dp = fmaf(-inv_mx, sym, 1.0f);
                    const int s = s4 * 4 + j;
                    float4 m0 = Ms4[s * 4 + 0];
                    float4 m1 = Ms4[s * 4 + 1];
                    float4 m2 = Ms4[s * 4 + 2];
                    float4 m3 = Ms4[s * 4 + 3];
                    rd[0]  = fmaf(dp, m0.x, rd[0]);  rd[1]  = fmaf(dp, m0.y, rd[1]);
                    rd[2]  = fmaf(dp, m0.z, rd[2]);  rd[3]  = fmaf(dp, m0.w, rd[3]);
                    rd[4]  = fmaf(dp, m1.x, rd[4]);  rd[5]  = fmaf(dp, m1.y, rd[5]);
                    rd[6]  = fmaf(dp, m1.z, rd[6]);  rd[7]  = fmaf(dp, m1.w, rd[7]);
                    rd[8]  = fmaf(dp, m2.x, rd[8]);  rd[9]  = fmaf(dp, m2.y, rd[9]);
                    rd[10] = fmaf(dp, m2.z, rd[10]); rd[11] = fmaf(dp, m2.w, rd[11]);
                    rd[12] = fmaf(dp, m3.x, rd[12]); rd[13] = fmaf(dp, m3.y, rd[13]);
                    rd[14] = fmaf(dp, m3.z, rd[14]); rd[15] = fmaf(dp, m3.w, rd[15]);
                }
            }
        }
        #pragma unroll
        for (int l = 0; l < 16; ++l) {
            float tens = cc1 + cC216[l] - 2.0f * rd[l];
            if (outer == 4) tens16[l] = tens;
            kreg[l] = exp2f(tens * (-kNEG_INV_EPS_LOG2E));
        }
        sinkhorn();   // first internal barrier orders stream reads vs next M-write
    }

    // ---- gw = sum tens * (u K v), alpha = exp(-gw) -------------------------
    float g = 0.f;
    #pragma unroll
    for (int l = 0; l < 16; ++l) g = fmaf(tens16[l] * kreg[l], vreg[l], g);
    g *= u_i;
    float gww = waveReduceSum(g);
    if (lane == 0) wred[wid] = gww;
    __syncthreads();
    if (tid == 0) {
        float gw = wred[0] + wred[1] + wred[2] + wred[3] + wred[4] + wred[5];
        alpha_out[head] = expf(-gw);
    }
}

// ---------------------------------------------------------------------------
// K2: sharpen prior_Q by alpha, build masked row-normalized attn [B,H,385,385]
// ---------------------------------------------------------------------------
__global__ __launch_bounds__(256) void k2_attn(
    const float* __restrict__ priorQ,    // [B,H,384,384]
    const float* __restrict__ alpha_in,  // [256]
    float* __restrict__ attn_out)        // [B,H,385,385]
{
    const int tid  = threadIdx.x;
    const int lane = tid & 63, wid = tid >> 6;
    const int head = blockIdx.x / 97;
    const int i    = (blockIdx.x % 97) * 4 + wid;
    if (i >= kS1) return;
    float* row = attn_out + (size_t)head * (kS1 * kS1) + (size_t)i * kS1;
    if (i == 0) {
        const float val = 1.0f / 384.0f;
        for (int j = lane; j < kS1; j += 64) row[j] = (j == 0) ? 0.f : val;
        return;
    }
    const float e = 1.0f + alpha_in[head];
    const float* q = priorQ + (size_t)head * (kS * kS) + (size_t)(i - 1) * kS;
    float p[6];
    float loc = 0.f, locd = 0.f;
    #pragma unroll
    for (int k = 0; k < 6; ++k) {
        int j = lane + k * 64;
        float qv = fmaxf(q[j], kEPS);
        float pv = exp2f(e * log2f(qv));
        p[k] = pv;
        loc += pv;
        if (j == i - 1) locd = pv;
    }
    float sum = loc, pd = locd;
    #pragma unroll
    for (int m = 1; m < 64; m <<= 1) { sum += __shfl_xor(sum, m); pd += __shfl_xor(pd, m); }
    const float qsum  = fmaxf(sum, kEPS);
    const float srow  = (sum - pd) / qsum;
    const float scale = 1.0f / (qsum * fmaxf(srow, kEPS));
    if (lane == 0) row[0] = 0.f;
    #pragma unroll
    for (int k = 0; k < 6; ++k) {
        int j = lane + k * 64;
        row[1 + j] = (j == i - 1) ? 0.f : p[k] * scale;
    }
}

// ---------------------------------------------------------------------------
// K3: vfull = nv @ v_w^T + v_b   ([12320,256] @ [256,256])
// ---------------------------------------------------------------------------
__global__ __launch_bounds__(256) void k3_vproj(
    const float* __restrict__ nv,    // [B*385,256]
    const float* __restrict__ vw,    // [256,256]
    const float* __restrict__ vb,    // [256]
    float* __restrict__ vfull)       // [B*385,256]
{
    __shared__ float At[64][17];
    __shared__ float Bt[256][17];
    const int tid = threadIdx.x;
    const int r0  = blockIdx.x * 64;
    const int tx  = tid & 31;       // cols c = tx + 32*ci
    const int ty  = tid >> 5;       // rows r = r0 + ty*8 + ri
    const int M   = kB * kS1;
    float acc[8][8];
    #pragma unroll
    for (int ri = 0; ri < 8; ++ri)
        #pragma unroll
        for (int ci = 0; ci < 8; ++ci) acc[ri][ci] = 0.f;

    for (int k0 = 0; k0 < 256; k0 += 16) {
        __syncthreads();
        for (int e = tid; e < 1024; e += 256) {
            int r = e >> 4, kk = e & 15;
            int rowi = r0 + r;
            At[r][kk] = (rowi < M) ? nv[rowi * 256 + k0 + kk] : 0.f;
        }
        for (int e = tid; e < 4096; e += 256) {
            int c = e >> 4, kk = e & 15;
            Bt[c][kk] = vw[c * 256 + k0 + kk];
        }
        __syncthreads();
        #pragma unroll
        for (int kk = 0; kk < 16; ++kk) {
            float av[8], bv[8];
            #pragma unroll
            for (int ri = 0; ri < 8; ++ri) av[ri] = At[ty * 8 + ri][kk];
            #pragma unroll
            for (int ci = 0; ci < 8; ++ci) bv[ci] = Bt[tx + 32 * ci][kk];
            #pragma unroll
            for (int ri = 0; ri < 8; ++ri)
                #pragma unroll
                for (int ci = 0; ci < 8; ++ci)
                    acc[ri][ci] = fmaf(av[ri], bv[ci], acc[ri][ci]);
        }
    }
    for (int ri = 0; ri < 8; ++ri) {
        int rowi = r0 + ty * 8 + ri;
        if (rowi < M) {
            #pragma unroll
            for (int ci = 0; ci < 8; ++ci) {
                int c = tx + 32 * ci;
                vfull[rowi * 256 + c] = acc[ri][ci] + vb[c];
            }
        }
    }
}

// ---------------------------------------------------------------------------
// K4: basis[b,i,c] = sum_j attn[b, c>>5, i, j] * vfull[b,j,c]
// 16-row tiles x 32-wide j-tiles: 800 blocks (was 416), pow-2 index math,
// 128B-coalesced attn loads, float4 vfull staging.
// ---------------------------------------------------------------------------
__global__ __launch_bounds__(256) void k4_ctx(
    const float* __restrict__ attn,    // [B,H,385,385]
    const float* __restrict__ vfull,   // [B*385,256]
    float* __restrict__ basis)         // [B,385,256]
{
    __shared__ __align__(16) float at[8 * 16 * 36];  // [h][ii][jj pad 36] = 18432B
    __shared__ __align__(16) float vt[32 * 256];     // 32768B
    const int tid = threadIdx.x;
    const int bb  = blockIdx.y;
    const int i0  = blockIdx.x * 16;
    const int h   = tid >> 5;
    float acc[16];
    #pragma unroll
    for (int i = 0; i < 16; ++i) acc[i] = 0.f;
    const float* attnB = attn + (size_t)bb * kH * kS1 * kS1;
    const float* vB    = vfull + (size_t)bb * kS1 * 256;

    for (int j0 = 0; j0 < kS1; j0 += 32) {
        __syncthreads();
        // attn tile: 8 heads x 16 rows x 32 j
        for (int e = tid; e < 4096; e += 256) {
            int jj = e & 31, ii = (e >> 5) & 15, hh = e >> 9;
            int gi = i0 + ii, gj = j0 + jj;
            at[(hh * 16 + ii) * 36 + jj] = (gi < kS1 && gj < kS1)
                ? attnB[(size_t)hh * kS1 * kS1 + (size_t)gi * kS1 + gj] : 0.f;
        }
        // vfull tile: 32 j x 256 c, float4
        for (int e = tid; e < 2048; e += 256) {
            int c4 = e & 63, jr = e >> 6;
            int gj = j0 + jr;
            float4 vv = (gj < kS1) ? *(const float4*)&vB[(size_t)gj * 256 + c4 * 4]
                                   : make_float4(0.f, 0.f, 0.f, 0.f);
            *(float4*)&vt[jr * 256 + c4 * 4] = vv;
        }
        __syncthreads();
        #pragma unroll
        for (int j4 = 0; j4 < 8; ++j4) {
            float v0 = vt[(j4 * 4 + 0) * 256 + tid];
            float v1 = vt[(j4 * 4 + 1) * 256 + tid];
            float v2 = vt[(j4 * 4 + 2) * 256 + tid];
            float v3 = vt[(j4 * 4 + 3) * 256 + tid];
            #pragma unroll
            for (int i = 0; i < 16; ++i) {
                float4 av = *(const float4*)&at[(h * 16 + i) * 36 + j4 * 4];
                acc[i] = fmaf(av.x, v0, fmaf(av.y, v1, fmaf(av.z, v2, fmaf(av.w, v3, acc[i]))));
            }
        }
    }
    #pragma unroll
    for (int i = 0; i < 16; ++i) {
        int gi = i0 + i;
        if (gi < kS1) basis[((size_t)bb * kS1 + gi) * 256 + tid] = acc[i];
    }
}

extern "C" void kernel_launch(void* const* d_in, const int* in_sizes, int n_in,
                              void* d_out, int out_size, void* d_ws, size_t ws_size,
                              hipStream_t stream) {
    (void)in_sizes; (void)n_in; (void)out_size; (void)ws_size;
    const float* nv    = (const float*)d_in[1];
    const float* sattn = (const float*)d_in[2];
    const float* pq    = (const float*)d_in[3];
    const float* dg    = (const float*)d_in[4];
    const float* bm    = (const float*)d_in[5];
    const float* vw    = (const float*)d_in[6];
    const float* vb    = (const float*)d_in[7];

    float* out   = (float*)d_out;
    float* basis = out;                                  // 32*385*256
    float* attn  = out + (size_t)kB * kS1 * kD;          // 32*8*385*385 (also SYM scratch)
    float* alpha = (float*)d_ws;
    float* vfull = (float*)((char*)d_ws + 4096);         // 12.6 MB

    k1a_sym<<<dim3(6, 256), 256, 0, stream>>>(sattn, attn);
    k1b_gw<<<256, 384, 0, stream>>>(dg, bm, attn, alpha);
    k2_attn<<<256 * 97, 256, 0, stream>>>(pq, alpha, attn);
    k3_vproj<<<193, 256, 0, stream>>>(nv, vw, vb, vfull);
    k4_ctx<<<dim3(25, 32), 256, 0, stream>>>(attn, vfull, basis);
}

// Round 3
// 1303.174 us; speedup vs baseline: 1.0237x; 1.0147x over previous
//
#include <hip/hip_runtime.h>
#include <math.h>

constexpr int kS  = 384;
constexpr int kS1 = 385;
constexpr int kH  = 8;
constexpr int kB  = 32;
constexpr int kD  = 256;
constexpr float kEPS = 1e-8f;
// (1/0.05) * log2(e)
constexpr float kNEG_INV_EPS_LOG2E = 28.853900817779268f;

__device__ __forceinline__ float waveReduceSum(float v) {
    #pragma unroll
    for (int m = 1; m < 64; m <<= 1) v += __shfl_xor(v, m);
    return v;
}
__device__ __forceinline__ float waveReduceMax(float v) {
    #pragma unroll
    for (int m = 1; m < 64; m <<= 1) v = fmaxf(v, __shfl_xor(v, m));
    return v;
}

// Per-head SYMp scratch lives in the attn output region (overwritten by k2).
// Layout: float4-chunk index (s4 in [0,96), i in [0,384)) at float4 slot
// (s4*384 + i) holding SYM[i][4*s4 .. 4*s4+3]. Lanes over i => coalesced.
// rs[384] at +147456, mxs[6] at +147840. Slack/head = 769 floats >= 390+3(pad).
__device__ __forceinline__ size_t symBase(int head) {
    return (size_t)head * (kS1 * kS1) + (size_t)((4 - (head & 3)) & 3);
}

// ---------------------------------------------------------------------------
// K1a: symmetrize P -> SYMp (lane-transposed chunk layout), rowsums, strip max.
// Block = one (head, 64-row strip). grid (6, 256), 256 threads.
// ---------------------------------------------------------------------------
__global__ __launch_bounds__(256) void k1a_sym(
    const float* __restrict__ shared_attn,   // [B,H,385,385]
    float* __restrict__ sym_ws)              // attn region (scratch)
{
    const int head = blockIdx.y;
    const int ti   = blockIdx.x;             // row-strip index 0..5
    const int tid  = threadIdx.x;
    const int c    = tid & 63;               // column-in-tile == lane
    const int w    = tid >> 6;               // wave 0..3

    __shared__ float tB[64 * 65];
    __shared__ float wredA[4];

    const float* P = shared_attn + (size_t)head * (kS1 * kS1);
    float* SYMp = sym_ws + symBase(head);
    float* rs   = SYMp + kS * kS;            // [384] rowsums
    float* mxs  = rs + kS;                   // [6] per-strip max

    float rs_part[16];
    #pragma unroll
    for (int k = 0; k < 16; ++k) rs_part[k] = 0.f;
    float mymax = 0.f;                       // P >= 0 (softmax), so 0 is safe

    for (int tj = 0; tj < 6; ++tj) {
        __syncthreads();
        // transpose source tile: P[tj-strip rows, ti-strip cols]
        for (int e = tid; e < 4096; e += 256) {
            int r = e >> 6, cc = e & 63;
            tB[r * 65 + cc] = P[(size_t)(1 + tj * 64 + r) * kS1 + (1 + ti * 64 + cc)];
        }
        __syncthreads();
        const int col = tj * 64 + c;
        const int s4  = col >> 2, cj = col & 3;
        #pragma unroll
        for (int k = 0; k < 16; ++k) {
            int r = w + 4 * k;               // rows w, w+4, ..., w+60 per wave
            float av = P[(size_t)(1 + ti * 64 + r) * kS1 + (1 + tj * 64 + c)];
            float v  = 0.5f * (av + tB[c * 65 + r]);
            mymax = fmaxf(mymax, v);
            rs_part[k] += v;
            SYMp[(size_t)(s4 * kS + ti * 64 + r) * 4 + cj] = v;
        }
    }
    // row r = w+4k is fully held by wave w (lane = column): wave reductions
    #pragma unroll
    for (int k = 0; k < 16; ++k) {
        float s = waveReduceSum(rs_part[k]);
        if (c == 0) rs[ti * 64 + w + 4 * k] = s;
    }
    float wm = waveReduceMax(mymax);
    if (c == 0) wredA[w] = wm;
    __syncthreads();
    if (tid == 0)
        mxs[ti] = fmaxf(fmaxf(wredA[0], wredA[1]), fmaxf(wredA[2], wredA[3]));
}

// ---------------------------------------------------------------------------
// K1b: per-(b,h) entropic GW -> alpha[head]. One block per head (256 blocks),
// 768 threads = (row i, s-half). Streaming reads SYMp fully coalesced
// (1KB/wave-load); rd partials combined via padded LDS. Sinkhorn/M-phase in
// lower 384 threads.
// ---------------------------------------------------------------------------
__global__ __launch_bounds__(768) void k1b_gw(
    const float* __restrict__ DG,            // [B,H,16,16]
    const float* __restrict__ bmarg,         // [B,H,16]
    float* __restrict__ sym_ws,              // attn region (scratch)
    float* __restrict__ alpha_out)           // [256]
{
    const int head = blockIdx.x;
    const int tid  = threadIdx.x;            // 0..767
    const int lane = tid & 63, wid = tid >> 6;
    const bool lower = (tid < kS);
    const int  i     = lower ? tid : tid - kS;   // row index
    const int  half  = lower ? 0 : 1;            // s-half

    __shared__ __align__(16) float Ms[kS * 16];      // 24576B
    __shared__ __align__(16) float pbuf[kS * 20];    // 30720B padded partials
    __shared__ float ravu[kS];
    __shared__ float part[6 * 16];
    __shared__ float C2l[256];
    __shared__ float bl16[16], cb16[16], cC216[16], vls[16];
    __shared__ float wred[6];

    float* SYMp = sym_ws + symBase(head);
    const float* rs  = SYMp + kS * kS;
    const float* mxp = rs + kS;

    if (tid < 256) C2l[tid] = DG[head * 256 + tid];
    if (tid >= 256 && tid < 272) bl16[tid - 256] = bmarg[head * 16 + (tid - 256)];

    float a_reg = 0.f, tloc = 0.f;
    if (lower) {
        tloc = rs[i];
        float tw = waveReduceSum(tloc);
        if (lane == 0) wred[wid] = tw;
    }
    __syncthreads();
    const float total = wred[0] + wred[1] + wred[2] + wred[3] + wred[4] + wred[5];
    const float mx = fmaxf(fmaxf(fmaxf(mxp[0], mxp[1]), fmaxf(mxp[2], mxp[3])),
                           fmaxf(mxp[4], mxp[5]));
    const float den_mx = fmaxf(mx, kEPS);
    const float inv_mx = 1.0f / den_mx;
    const float Sdeg   = total * inv_mx;
    const float den_a  = fmaxf(Sdeg, kEPS);
    if (lower) {
        a_reg = (tloc * inv_mx) / den_a;
        ravu[i] = a_reg;
    }
    if (tid < 16) {
        float cb = 0.f, cc2 = 0.f;
        #pragma unroll
        for (int k = 0; k < 16; ++k) {
            cb += bl16[k] * C2l[tid * 16 + k];          // cb[l]  = sum_k b_k C2[l,k]
            float c2 = C2l[k * 16 + tid];               // C2[k,l]
            cc2 = fmaf(bl16[k] * c2, c2, cc2);          // cC2[l] = sum_k b_k C2[k,l]^2
        }
        cb16[tid] = cb; cC216[tid] = cc2;
    }
    __syncthreads();

    const float4* __restrict__ symp = (const float4*)SYMp;
    const int s4beg = half * 48, s4end = s4beg + 48;

    // ---- outer iter 1 (closed form: T = a (x) b), coalesced stream --------
    float t1 = 0.f, t2 = 0.f;
    #pragma unroll 2
    for (int s4 = s4beg; s4 < s4end; ++s4) {
        float4 v4 = symp[s4 * kS + i];
        const float* av = &ravu[s4 * 4];
        float dp;
        dp = fmaf(-inv_mx, v4.x, 1.0f); t1 = fmaf(dp, av[0], t1); t2 = fmaf(dp * dp, av[0], t2);
        dp = fmaf(-inv_mx, v4.y, 1.0f); t1 = fmaf(dp, av[1], t1); t2 = fmaf(dp * dp, av[1], t2);
        dp = fmaf(-inv_mx, v4.z, 1.0f); t1 = fmaf(dp, av[2], t1); t2 = fmaf(dp * dp, av[2], t2);
        dp = fmaf(-inv_mx, v4.w, 1.0f); t1 = fmaf(dp, av[3], t1); t2 = fmaf(dp * dp, av[3], t2);
    }
    if (!lower) { pbuf[i] = t1; pbuf[512 + i] = t2; }
    __syncthreads();

    float kreg[16], vreg[16];
    float u_i = 0.f, cc1 = 0.f;
    if (lower) {
        t1 += pbuf[i];
        t2 += pbuf[512 + i];
        cc1 = t2;
        #pragma unroll
        for (int l = 0; l < 16; ++l)
            kreg[l] = exp2f((cc1 + cC216[l] - 2.0f * cb16[l] * t1) * (-kNEG_INV_EPS_LOG2E));
    }

    auto sinkhorn = [&]() {
        #pragma unroll
        for (int l = 0; l < 16; ++l) vreg[l] = 1.0f;
        for (int it = 0; it < 20; ++it) {
            if (lower) {
                float su = 0.f;
                #pragma unroll
                for (int l = 0; l < 16; ++l) su = fmaf(kreg[l], vreg[l], su);
                u_i = a_reg / fmaxf(su, 1e-30f);
                // colsum dn[l] = sum_s K[s,l] u_s : wave-level shuffle partials
                #pragma unroll
                for (int l = 0; l < 16; ++l) {
                    float t = waveReduceSum(kreg[l] * u_i);
                    if (lane == 0) part[wid * 16 + l] = t;
                }
            }
            __syncthreads();
            if (tid < 16) {
                float dn = part[tid] + part[16 + tid] + part[32 + tid] +
                           part[48 + tid] + part[64 + tid] + part[80 + tid];
                vls[tid] = bl16[tid] / fmaxf(dn, 1e-30f);
            }
            __syncthreads();
            #pragma unroll
            for (int l = 0; l < 16; ++l) vreg[l] = vls[l];
        }
    };

    sinkhorn();

    float tens16[16];
    #pragma unroll
    for (int l = 0; l < 16; ++l) tens16[l] = 0.f;

    for (int outer = 1; outer < 5; ++outer) {
        // ---- M-phase: Ms[s][l] = u_s * sum_k K[s,k] v_k C2[l,k] ----------
        if (lower) {
            float wk[16];
            #pragma unroll
            for (int k = 0; k < 16; ++k) wk[k] = kreg[k] * vreg[k];
            float m[16];
            #pragma unroll
            for (int l = 0; l < 16; ++l) {
                float acc = 0.f;
                #pragma unroll
                for (int k = 0; k < 16; ++k) acc = fmaf(wk[k], C2l[l * 16 + k], acc);
                m[l] = acc * u_i;
            }
            float4* Ms4w = (float4*)Ms;
            Ms4w[i * 4 + 0] = make_float4(m[0],  m[1],  m[2],  m[3]);
            Ms4w[i * 4 + 1] = make_float4(m[4],  m[5],  m[6],  m[7]);
            Ms4w[i * 4 + 2] = make_float4(m[8],  m[9],  m[10], m[11]);
            Ms4w[i * 4 + 3] = make_float4(m[12], m[13], m[14], m[15]);
        }
        __syncthreads();
        // ---- stream: rd[l] = sum_s DP[i,s] * Ms[s][l], coalesced ---------
        float rd[16];
        #pragma unroll
        for (int l = 0; l < 16; ++l) rd[l] = 0.f;
        {
            const float4* Ms4 = (const float4*)Ms;
            #pragma unroll 2
            for (int s4 = s4beg; s4 < s4end; ++s4) {
                float4 v4 = symp[s4 * kS + i];
                #pragma unroll
                for (int j = 0; j < 4; ++j) {
                    float sym = (j == 0) ? v4.x : (j == 1) ? v4.y : (j == 2) ? v4.z : v4.w;
                    float dp = fmaf(-inv_mx, sym, 1.0f);
                    const int s = s4 * 4 + j;
                    float4 m0 = Ms4[s * 4 + 0];
                    float4 m1 = Ms4[s * 4 + 1];
                    float4 m2 = Ms4[s * 4 + 2];
                    float4 m3 = Ms4[s * 4 + 3];
                    rd[0]  = fmaf(dp, m0.x, rd[0]);  rd[1]  = fmaf(dp, m0.y, rd[1]);
                    rd[2]  = fmaf(dp, m0.z, rd[2]);  rd[3]  = fmaf(dp, m0.w, rd[3]);
                    rd[4]  = fmaf(dp, m1.x, rd[4]);  rd[5]  = fmaf(dp, m1.y, rd[5]);
                    rd[6]  = fmaf(dp, m1.z, rd[6]);  rd[7]  = fmaf(dp, m1.w, rd[7]);
                    rd[8]  = fmaf(dp, m2.x, rd[8]);  rd[9]  = fmaf(dp, m2.y, rd[9]);
                    rd[10] = fmaf(dp, m2.z, rd[10]); rd[11] = fmaf(dp, m2.w, rd[11]);
                    rd[12] = fmaf(dp, m3.x, rd[12]); rd[13] = fmaf(dp, m3.y, rd[13]);
                    rd[14] = fmaf(dp, m3.z, rd[14]); rd[15] = fmaf(dp, m3.w, rd[15]);
                }
            }
        }
        if (!lower) {
            float4* pb = (float4*)&pbuf[i * 20];
            pb[0] = make_float4(rd[0],  rd[1],  rd[2],  rd[3]);
            pb[1] = make_float4(rd[4],  rd[5],  rd[6],  rd[7]);
            pb[2] = make_float4(rd[8],  rd[9],  rd[10], rd[11]);
            pb[3] = make_float4(rd[12], rd[13], rd[14], rd[15]);
        }
        __syncthreads();
        if (lower) {
            const float4* pb = (const float4*)&pbuf[i * 20];
            float4 p0 = pb[0], p1 = pb[1], p2 = pb[2], p3 = pb[3];
            rd[0] += p0.x; rd[1] += p0.y; rd[2]  += p0.z; rd[3]  += p0.w;
            rd[4] += p1.x; rd[5] += p1.y; rd[6]  += p1.z; rd[7]  += p1.w;
            rd[8] += p2.x; rd[9] += p2.y; rd[10] += p2.z; rd[11] += p2.w;
            rd[12] += p3.x; rd[13] += p3.y; rd[14] += p3.z; rd[15] += p3.w;
            #pragma unroll
            for (int l = 0; l < 16; ++l) {
                float tens = cc1 + cC216[l] - 2.0f * rd[l];
                if (outer == 4) tens16[l] = tens;
                kreg[l] = exp2f(tens * (-kNEG_INV_EPS_LOG2E));
            }
        }
        sinkhorn();   // internal barriers also order pbuf/Ms reuse
    }

    // ---- gw = sum tens * (u K v), alpha = exp(-gw) -------------------------
    if (lower) {
        float g = 0.f;
        #pragma unroll
        for (int l = 0; l < 16; ++l) g = fmaf(tens16[l] * kreg[l], vreg[l], g);
        g *= u_i;
        float gww = waveReduceSum(g);
        if (lane == 0) wred[wid] = gww;
    }
    __syncthreads();
    if (tid == 0) {
        float gw = wred[0] + wred[1] + wred[2] + wred[3] + wred[4] + wred[5];
        alpha_out[head] = expf(-gw);
    }
}

// ---------------------------------------------------------------------------
// K2: sharpen prior_Q by alpha, build masked row-normalized attn [B,H,385,385]
// ---------------------------------------------------------------------------
__global__ __launch_bounds__(256) void k2_attn(
    const float* __restrict__ priorQ,    // [B,H,384,384]
    const float* __restrict__ alpha_in,  // [256]
    float* __restrict__ attn_out)        // [B,H,385,385]
{
    const int tid  = threadIdx.x;
    const int lane = tid & 63, wid = tid >> 6;
    const int head = blockIdx.x / 97;
    const int i    = (blockIdx.x % 97) * 4 + wid;
    if (i >= kS1) return;
    float* row = attn_out + (size_t)head * (kS1 * kS1) + (size_t)i * kS1;
    if (i == 0) {
        const float val = 1.0f / 384.0f;
        for (int j = lane; j < kS1; j += 64) row[j] = (j == 0) ? 0.f : val;
        return;
    }
    const float e = 1.0f + alpha_in[head];
    const float* q = priorQ + (size_t)head * (kS * kS) + (size_t)(i - 1) * kS;
    float p[6];
    float loc = 0.f, locd = 0.f;
    #pragma unroll
    for (int k = 0; k < 6; ++k) {
        int j = lane + k * 64;
        float qv = fmaxf(q[j], kEPS);
        float pv = exp2f(e * log2f(qv));
        p[k] = pv;
        loc += pv;
        if (j == i - 1) locd = pv;
    }
    float sum = loc, pd = locd;
    #pragma unroll
    for (int m = 1; m < 64; m <<= 1) { sum += __shfl_xor(sum, m); pd += __shfl_xor(pd, m); }
    const float qsum  = fmaxf(sum, kEPS);
    const float srow  = (sum - pd) / qsum;
    const float scale = 1.0f / (qsum * fmaxf(srow, kEPS));
    if (lane == 0) row[0] = 0.f;
    #pragma unroll
    for (int k = 0; k < 6; ++k) {
        int j = lane + k * 64;
        row[1 + j] = (j == i - 1) ? 0.f : p[k] * scale;
    }
}

// ---------------------------------------------------------------------------
// K3: vfull = nv @ v_w^T + v_b   ([12320,256] @ [256,256])
// ---------------------------------------------------------------------------
__global__ __launch_bounds__(256) void k3_vproj(
    const float* __restrict__ nv,    // [B*385,256]
    const float* __restrict__ vw,    // [256,256]
    const float* __restrict__ vb,    // [256]
    float* __restrict__ vfull)       // [B*385,256]
{
    __shared__ float At[64][17];
    __shared__ float Bt[256][17];
    const int tid = threadIdx.x;
    const int r0  = blockIdx.x * 64;
    const int tx  = tid & 31;       // cols c = tx + 32*ci
    const int ty  = tid >> 5;       // rows r = r0 + ty*8 + ri
    const int M   = kB * kS1;
    float acc[8][8];
    #pragma unroll
    for (int ri = 0; ri < 8; ++ri)
        #pragma unroll
        for (int ci = 0; ci < 8; ++ci) acc[ri][ci] = 0.f;

    for (int k0 = 0; k0 < 256; k0 += 16) {
        __syncthreads();
        for (int e = tid; e < 1024; e += 256) {
            int r = e >> 4, kk = e & 15;
            int rowi = r0 + r;
            At[r][kk] = (rowi < M) ? nv[rowi * 256 + k0 + kk] : 0.f;
        }
        for (int e = tid; e < 4096; e += 256) {
            int c = e >> 4, kk = e & 15;
            Bt[c][kk] = vw[c * 256 + k0 + kk];
        }
        __syncthreads();
        #pragma unroll
        for (int kk = 0; kk < 16; ++kk) {
            float av[8], bv[8];
            #pragma unroll
            for (int ri = 0; ri < 8; ++ri) av[ri] = At[ty * 8 + ri][kk];
            #pragma unroll
            for (int ci = 0; ci < 8; ++ci) bv[ci] = Bt[tx + 32 * ci][kk];
            #pragma unroll
            for (int ri = 0; ri < 8; ++ri)
                #pragma unroll
                for (int ci = 0; ci < 8; ++ci)
                    acc[ri][ci] = fmaf(av[ri], bv[ci], acc[ri][ci]);
        }
    }
    for (int ri = 0; ri < 8; ++ri) {
        int rowi = r0 + ty * 8 + ri;
        if (rowi < M) {
            #pragma unroll
            for (int ci = 0; ci < 8; ++ci) {
                int c = tx + 32 * ci;
                vfull[rowi * 256 + c] = acc[ri][ci] + vb[c];
            }
        }
    }
}

// ---------------------------------------------------------------------------
// K4: basis[b,i,c] = sum_j attn[b, c>>5, i, j] * vfull[b,j,c]
// ---------------------------------------------------------------------------
__global__ __launch_bounds__(256) void k4_ctx(
    const float* __restrict__ attn,    // [B,H,385,385]
    const float* __restrict__ vfull,   // [B*385,256]
    float* __restrict__ basis)         // [B,385,256]
{
    __shared__ __align__(16) float at[8 * 16 * 36];  // [h][ii][jj pad 36] = 18432B
    __shared__ __align__(16) float vt[32 * 256];     // 32768B
    const int tid = threadIdx.x;
    const int bb  = blockIdx.y;
    const int i0  = blockIdx.x * 16;
    const int h   = tid >> 5;
    float acc[16];
    #pragma unroll
    for (int i = 0; i < 16; ++i) acc[i] = 0.f;
    const float* attnB = attn + (size_t)bb * kH * kS1 * kS1;
    const float* vB    = vfull + (size_t)bb * kS1 * 256;

    for (int j0 = 0; j0 < kS1; j0 += 32) {
        __syncthreads();
        // attn tile: 8 heads x 16 rows x 32 j
        for (int e = tid; e < 4096; e += 256) {
            int jj = e & 31, ii = (e >> 5) & 15, hh = e >> 9;
            int gi = i0 + ii, gj = j0 + jj;
            at[(hh * 16 + ii) * 36 + jj] = (gi < kS1 && gj < kS1)
                ? attnB[(size_t)hh * kS1 * kS1 + (size_t)gi * kS1 + gj] : 0.f;
        }
        // vfull tile: 32 j x 256 c, float4
        for (int e = tid; e < 2048; e += 256) {
            int c4 = e & 63, jr = e >> 6;
            int gj = j0 + jr;
            float4 vv = (gj < kS1) ? *(const float4*)&vB[(size_t)gj * 256 + c4 * 4]
                                   : make_float4(0.f, 0.f, 0.f, 0.f);
            *(float4*)&vt[jr * 256 + c4 * 4] = vv;
        }
        __syncthreads();
        #pragma unroll
        for (int j4 = 0; j4 < 8; ++j4) {
            float v0 = vt[(j4 * 4 + 0) * 256 + tid];
            float v1 = vt[(j4 * 4 + 1) * 256 + tid];
            float v2 = vt[(j4 * 4 + 2) * 256 + tid];
            float v3 = vt[(j4 * 4 + 3) * 256 + tid];
            #pragma unroll
            for (int i = 0; i < 16; ++i) {
                float4 av = *(const float4*)&at[(h * 16 + i) * 36 + j4 * 4];
                acc[i] = fmaf(av.x, v0, fmaf(av.y, v1, fmaf(av.z, v2, fmaf(av.w, v3, acc[i]))));
            }
        }
    }
    #pragma unroll
    for (int i = 0; i < 16; ++i) {
        int gi = i0 + i;
        if (gi < kS1) basis[((size_t)bb * kS1 + gi) * 256 + tid] = acc[i];
    }
}

extern "C" void kernel_launch(void* const* d_in, const int* in_sizes, int n_in,
                              void* d_out, int out_size, void* d_ws, size_t ws_size,
                              hipStream_t stream) {
    (void)in_sizes; (void)n_in; (void)out_size; (void)ws_size;
    const float* nv    = (const float*)d_in[1];
    const float* sattn = (const float*)d_in[2];
    const float* pq    = (const float*)d_in[3];
    const float* dg    = (const float*)d_in[4];
    const float* bm    = (const float*)d_in[5];
    const float* vw    = (const float*)d_in[6];
    const float* vb    = (const float*)d_in[7];

    float* out   = (float*)d_out;
    float* basis = out;                                  // 32*385*256
    float* attn  = out + (size_t)kB * kS1 * kD;          // 32*8*385*385 (also SYMp scratch)
    float* alpha = (float*)d_ws;
    float* vfull = (float*)((char*)d_ws + 4096);         // 12.6 MB

    k1a_sym<<<dim3(6, 256), 256, 0, stream>>>(sattn, attn);
    k1b_gw<<<256, 768, 0, stream>>>(dg, bm, attn, alpha);
    k2_attn<<<256 * 97, 256, 0, stream>>>(pq, alpha, attn);
    k3_vproj<<<193, 256, 0, stream>>>(nv, vw, vb, vfull);
    k4_ctx<<<dim3(25, 32), 256, 0, stream>>>(attn, vfull, basis);
}